// Round 9
// baseline (626.574 us; speedup 1.0000x reference)
//
#include <hip/hip_runtime.h>
#include <hip/hip_bf16.h>
#include <hip/hip_fp16.h>

// Problem constants
#define NB 64
#define NT 256
#define TC 16
#define NL 25
#define NWORDS 16384   // NB*NT
#define DWd 150        // word-LSTM input dim
#define WEd 100
#define WPB 5          // words per k_char block

typedef _Float16 h2_t __attribute__((ext_vector_type(2)));

__device__ __forceinline__ float sigf(float x){ return __fdividef(1.f, 1.f + __expf(-x)); }
__device__ __forceinline__ float tanhf_(float x){
    float ax = fabsf(x);
    float e = __expf(-2.f*ax);                 // e in (0,1], overflow-safe
    float r = (1.f - e) * __fdividef(1.f, 1.f + e);
    return copysignf(r, x);
}

#if __has_builtin(__builtin_amdgcn_fdot2)
__device__ __forceinline__ float fdot2_(h2_t a, h2_t b, float c){
  return __builtin_amdgcn_fdot2(a, b, c, false);
}
#else
__device__ __forceinline__ float fdot2_(h2_t a, h2_t b, float c){
  return c + (float)a.x*(float)b.x + (float)a.y*(float)b.y;
}
#endif

// ---------------- Kernel 0: gxc[(c,d)][col] = cb_d[col] + sum_k char_emb[c][k]*cWih_d[k*100+col]
__global__ void k_gxc(const float* __restrict__ char_emb,
                      const float* __restrict__ cWih_f, const float* __restrict__ cb_f,
                      const float* __restrict__ cWih_b, const float* __restrict__ cb_b,
                      float* __restrict__ gxc){
  int i = blockIdx.x*blockDim.x + threadIdx.x;
  if (i >= 128*2*100) return;
  int col = i % 100; int d = (i/100) & 1; int c = i/200;
  const float* Wih = d ? cWih_b : cWih_f;
  const float* bb  = d ? cb_b  : cb_f;
  float acc = bb[col];
  #pragma unroll
  for (int k=0;k<25;k++) acc += char_emb[c*25+k]*Wih[k*100+col];
  gxc[i] = acc;
}

// ---------------- Kernel 1: char BiLSTM, thread = (word_in_block, gate_col).
__global__ __launch_bounds__(512) void k_char(const int* __restrict__ char_tensor,
   const int* __restrict__ char_lengths,
   const float* __restrict__ cWhh_f, const float* __restrict__ cWhh_b,
   const float* __restrict__ gxc, float* __restrict__ cf){
  __shared__ float h_lds[WPB][28];    // rows padded to 28 (16B-aligned float4 reads)
  __shared__ float act[WPB][100];
  __shared__ int   chars[WPB][TC];
  __shared__ int   lens[WPB];
  int tid = threadIdx.x;
  int d  = blockIdx.x & 1;
  int wb = blockIdx.x >> 1;           // 0..3276
  int w0 = wb*WPB;
  if (tid < WPB*TC){
    int ww = w0 + tid/TC;
    int cw = ww < NWORDS ? ww : NWORDS-1;
    chars[tid/TC][tid%TC] = char_tensor[cw*TC + (tid%TC)];
  }
  if (tid < WPB){
    int ww = w0 + tid;
    lens[tid] = char_lengths[ww < NWORDS ? ww : NWORDS-1];
  }
  int wsub = tid/100;                 // 0..4 for tid<500
  int j    = tid - wsub*100;          // gate col 0..99
  bool gate_thr = tid < WPB*100;
  const float* Wh = d ? cWhh_b : cWhh_f;
  float wcol[25];
  if (gate_thr){
    #pragma unroll
    for (int k=0;k<25;k++) wcol[k] = Wh[k*100 + j];
  }
  if (gate_thr && j < 28) h_lds[wsub][j] = 0.f;
  float c_reg = 0.f, h_last = 0.f;
  __syncthreads();
  int len = gate_thr ? lens[wsub] : 1;
  bool isg = (j >= 50) && (j < 75);
  float g_all[TC];
  if (gate_thr){
    #pragma unroll
    for (int t=0;t<TC;t++){
      int ci = d ? (len-1-t) : t;
      if (ci < 0 || ci >= TC) ci = 0;
      int cidx = chars[wsub][ci];
      g_all[t] = gxc[(size_t)(cidx*2+d)*100 + j];
    }
  }
  for (int t=0;t<TC;t++){
    if (gate_thr){
      float a = g_all[t];
      const float4* h4 = (const float4*)h_lds[wsub];
      #pragma unroll
      for (int kq=0;kq<6;kq++){
        float4 hq = h4[kq];
        a += hq.x*wcol[4*kq] + hq.y*wcol[4*kq+1] + hq.z*wcol[4*kq+2] + hq.w*wcol[4*kq+3];
      }
      a += h_lds[wsub][24]*wcol[24];
      act[wsub][j] = isg ? tanhf_(a) : sigf(a);
    }
    __syncthreads();
    if (gate_thr && j < 25 && t < len){
      float si = act[wsub][j], sf = act[wsub][25+j], sg = act[wsub][50+j], so = act[wsub][75+j];
      c_reg = sf*c_reg + si*sg;
      float hv = so*tanhf_(c_reg);
      h_lds[wsub][j] = hv;
      h_last = hv;
    }
    __syncthreads();
  }
  if (gate_thr && j < 25){
    int w = w0 + wsub;
    if (w < NWORDS) cf[(size_t)w*56 + d*28 + j] = h_last;
  }
}

// ---------------- Kernel 2: x[p][150] = word_emb[tok[p]] ++ cf[recover[p]] (cf stride 56)
__global__ void k_buildx(const int* __restrict__ tok, const int* __restrict__ recover,
                         const float* __restrict__ word_emb, const float* __restrict__ cf,
                         float* __restrict__ x){
  long i = (long)blockIdx.x*blockDim.x + threadIdx.x;
  if (i >= (long)NWORDS*DWd) return;
  int p = (int)(i/DWd); int e = (int)(i - (long)p*DWd);
  float v;
  if (e < WEd) v = word_emb[(long)tok[p]*WEd + e];
  else {
    int cidx = e - WEd;           // 0..49
    int dd = cidx / 25; int uu = cidx - dd*25;
    v = cf[(size_t)recover[p]*56 + dd*28 + uu];
  }
  x[i] = v;
}

// ---------------- Kernel 3: gx[d][p][400] = wb_d + x[p] @ wWih_d (fp32 tiled, M=16384,N=800,K=150)
__global__ __launch_bounds__(256) void k_wih(const float* __restrict__ x,
    const float* __restrict__ Wf, const float* __restrict__ bf,
    const float* __restrict__ Wb, const float* __restrict__ bbias,
    float* __restrict__ gx){
  __shared__ float As[150][36];
  int tid = threadIdx.x;
  int m0 = (blockIdx.x>>2)*32;
  int nt = blockIdx.x & 3;
  int n0 = nt*256;
  for (int i=tid; i<32*150; i+=256){
    int r = i/150; int k = i - r*150;
    As[k][r] = x[(long)(m0+r)*150 + k];
  }
  __syncthreads();
  int tn = tid & 31; int tm = tid >> 5;
  int j0 = n0 + tn*8;
  bool colok = j0 < 800;
  int d = (j0 >= 400) ? 1 : 0;
  const float* W = d ? Wb : Wf;
  int jc = j0 - d*400;
  float acc[4][8];
  #pragma unroll
  for (int mi=0;mi<4;mi++)
    #pragma unroll
    for (int ni=0;ni<8;ni++) acc[mi][ni]=0.f;
  if (colok){
    for (int k=0;k<150;k++){
      float4 b0 = *(const float4*)&W[k*400 + jc];
      float4 b1 = *(const float4*)&W[k*400 + jc + 4];
      float4 a4 = *(const float4*)&As[k][tm*4];
      float av[4] = {a4.x,a4.y,a4.z,a4.w};
      float bv[8] = {b0.x,b0.y,b0.z,b0.w,b1.x,b1.y,b1.z,b1.w};
      #pragma unroll
      for (int mi=0;mi<4;mi++)
        #pragma unroll
        for (int ni=0;ni<8;ni++) acc[mi][ni] += av[mi]*bv[ni];
    }
    const float* bptr = d ? bbias : bf;
    float bias[8];
    #pragma unroll
    for (int ni=0;ni<8;ni++) bias[ni] = bptr[jc+ni];
    #pragma unroll
    for (int mi=0;mi<4;mi++){
      int p = m0 + tm*4 + mi;
      float* orow = gx + ((long)d*NWORDS + p)*400 + jc;
      #pragma unroll
      for (int ni=0;ni<8;ni++) orow[ni] = acc[mi][ni] + bias[ni];
    }
  }
}

// ---------------- Kernel 4: word LSTM recurrence v7.
// KEY: no per-step VMEM -> the vmcnt(0) drain before every s_barrier (which
// serialized v4-v6 at ~230us) disappears. gx is staged per 16-step chunk into
// double-buffered LDS; h history buffered in LDS, flushed per chunk.
// thread = (unit u, k-half): 100 weight VGPRs; each thread reads half of h
// (7 LDS instrs); pair partial-sums combined via __shfl_xor(.,1).
__global__ __launch_bounds__(256, 1) void k_wlstm(const float* __restrict__ gx,
     const float* __restrict__ Whf, const float* __restrict__ Whb,
     float* __restrict__ hseq){
  __shared__ float gxs[2][16][400];          // 51.2 KB, gx chunk double-buffer
  __shared__ float hout[2][16][100];         // 12.8 KB, h history double-buffer
  __shared__ __align__(16) _Float16 h16[2][2][64];  // [t-parity][k-half][50 used]
  int tid = threadIdx.x;
  int s = blockIdx.x & 63; int d = blockIdx.x >> 6;
  const float* Wh = d ? Whb : Whf;
  int u  = tid >> 1;       // unit 0..127 (valid <100)
  int hf = tid & 1;        // k-half
  bool act_thr = tid < 200;
  // weights: 4 gates x 25 h2 over k = hf*50 .. hf*50+49
  h2_t wi[25], wf[25], wg[25], wo[25];
  if (act_thr){
    int kb = hf*50;
    #pragma unroll
    for (int jj=0;jj<25;jj++){
      int r0 = (kb+2*jj)*400, r1 = (kb+2*jj+1)*400;
      wi[jj] = (h2_t){(_Float16)Wh[r0 + u],       (_Float16)Wh[r1 + u]};
      wf[jj] = (h2_t){(_Float16)Wh[r0 + 100 + u], (_Float16)Wh[r1 + 100 + u]};
      wg[jj] = (h2_t){(_Float16)Wh[r0 + 200 + u], (_Float16)Wh[r1 + 200 + u]};
      wo[jj] = (h2_t){(_Float16)Wh[r0 + 300 + u], (_Float16)Wh[r1 + 300 + u]};
    }
  }
  ((_Float16*)h16)[tid] = (_Float16)0.f;     // 2*2*64 = 256 entries
  float c_reg = 0.f;
  const float* gxd = gxd = gx + ((long)d*NWORDS + (long)s*256)*400;
  long hseq_base = (long)d*NWORDS + (long)s*256;

  float4 st[7];
#define ISSUE_STAGE(C) { int _b=(C)*16; _Pragma("unroll") \
  for (int q=0;q<7;q++){ int L=q*256+tid; if (L<1600){ \
    int sl=L/100, c4=L-sl*100; int tt = d ? (255-(_b+sl)) : (_b+sl); \
    st[q] = *(const float4*)&gxd[(long)tt*400 + c4*4]; } } }
#define WRITE_STAGE(B) { _Pragma("unroll") \
  for (int q=0;q<7;q++){ int L=q*256+tid; if (L<1600){ \
    int sl=L/100, c4=L-sl*100; *(float4*)&gxs[B][sl][c4*4] = st[q]; } } }
#define FLUSH(CH, HB) { _Pragma("unroll") \
  for (int q=0;q<7;q++){ int L=q*256+tid; if (L<1600){ \
    int sl=L/100, uu=L-sl*100; int t=(CH)*16+sl; int ttc = d ? (255-t) : t; \
    hseq[(hseq_base + ttc)*100 + uu] = hout[HB][sl][uu]; } } }

  ISSUE_STAGE(0)
  WRITE_STAGE(0)
  __syncthreads();

  for (int ch=0; ch<16; ch++){
    int gb = ch & 1;
    if (ch < 15) ISSUE_STAGE(ch+1)
    if (ch > 0)  FLUSH(ch-1, gb^1)
    for (int sl=0; sl<16; sl++){
      int t = ch*16 + sl;
      int rb = t & 1, wb = rb ^ 1;
      if (act_thr){
        // read my k-half of h (50 f16 = 25 h2)
        h2_t hh[25];
        const float4* hb = (const float4*)&h16[rb][hf][0];
        #pragma unroll
        for (int q=0;q<6;q++) ((float4*)hh)[q] = hb[q];
        hh[24] = ((const h2_t*)&h16[rb][hf][0])[24];
        float pi=0.f, pf=0.f, pg=0.f, po=0.f;
        #pragma unroll
        for (int jj=0;jj<25;jj++){
          h2_t hv = hh[jj];
          pi = fdot2_(hv, wi[jj], pi);
          pf = fdot2_(hv, wf[jj], pf);
          pg = fdot2_(hv, wg[jj], pg);
          po = fdot2_(hv, wo[jj], po);
        }
        if (hf == 0){
          pi += gxs[gb][sl][u];       pf += gxs[gb][sl][100+u];
          pg += gxs[gb][sl][200+u];   po += gxs[gb][sl][300+u];
        }
        float fi = pi + __shfl_xor(pi, 1);
        float ff = pf + __shfl_xor(pf, 1);
        float fg = pg + __shfl_xor(pg, 1);
        float fo = po + __shfl_xor(po, 1);
        float A = 0.f;
        float sf_ = 0.f, so_ = 0.f;
        if (hf == 0) A = sigf(fi)*tanhf_(fg);
        else { sf_ = sigf(ff); so_ = sigf(fo); }
        float Ax = __shfl_xor(A, 1);
        if (hf == 1){
          c_reg = sf_*c_reg + Ax;
          float hv = so_*tanhf_(c_reg);
          int half = (u >= 50) ? 1 : 0;
          h16[wb][half][u - half*50] = (_Float16)hv;
          hout[gb][sl][u] = hv;
        }
      }
      __syncthreads();
      if (sl == 0 && ch < 15) WRITE_STAGE(gb^1)
    }
  }
  FLUSH(15, 1)
#undef ISSUE_STAGE
#undef WRITE_STAGE
#undef FLUSH
}

// ---------------- Kernel 5: emissions em[p][25] = b_tag + concat(h_f,h_b)[p] @ W_tag
__global__ __launch_bounds__(256) void k_em(const float* __restrict__ hseq,
    const float* __restrict__ Wtag, const float* __restrict__ btag,
    float* __restrict__ em){
  __shared__ float hrow[8][200];
  __shared__ float Ws[5000];
  int tid = threadIdx.x;
  for (int i=tid;i<5000;i+=256) Ws[i] = Wtag[i];
  int p0 = blockIdx.x*8;
  for (int i=tid;i<8*200;i+=256){
    int r = i/200; int k = i - r*200;
    int p = p0+r;
    hrow[r][k] = (k<100) ? hseq[(long)p*100+k] : hseq[((long)NWORDS + p)*100 + (k-100)];
  }
  __syncthreads();
  int r = tid>>5; int c = tid&31;
  if (c<25){
    float acc = btag[c];
    for (int k=0;k<200;k++) acc += hrow[r][k]*Ws[k*25+c];
    em[(long)(p0+r)*25 + c] = acc;
  }
}

// ---------------- Kernel 6: CRF per sequence: part[s] = logZ - gold.
__global__ __launch_bounds__(64) void k_crf(const float* __restrict__ em,
    const int* __restrict__ tag, const float* __restrict__ trans,
    const float* __restrict__ start, const float* __restrict__ endv,
    float* __restrict__ part){
  int s = blockIdx.x;
  int lane = threadIdx.x;
  int j = lane & 31; int kg = lane >> 5;
  int k0 = kg ? 13 : 0; int kcnt = kg ? 12 : 13;
  const float* emb = em + (long)s*256*25;
  float tr[13];
  #pragma unroll
  for (int kk=0;kk<13;kk++){
    int k = k0+kk;
    tr[kk] = (k<25 && j<25) ? trans[k*25+j] : 0.f;
  }
  float alpha = (j<25) ? (start[j] + emb[j]) : -1e30f;
  float enext = (j<25) ? emb[25 + j] : 0.f;
  for (int t=1;t<256;t++){
    float ecur = enext;
    if (t<255 && j<25) enext = emb[(t+1)*25 + j];
    float m = -1e30f;
    #pragma unroll
    for (int kk=0;kk<13;kk++){
      if (kk<kcnt){
        float a = __shfl(alpha, k0+kk, 64);
        m = fmaxf(m, a + tr[kk]);
      }
    }
    m = fmaxf(m, __shfl_xor(m, 32, 64));
    float ssum = 0.f;
    #pragma unroll
    for (int kk=0;kk<13;kk++){
      if (kk<kcnt){
        float a = __shfl(alpha, k0+kk, 64);
        ssum += __expf(a + tr[kk] - m);
      }
    }
    ssum += __shfl_xor(ssum, 32, 64);
    float anew = __logf(ssum) + m + ecur;
    alpha = (j<25) ? anew : -1e30f;
  }
  float val = (j<25 && kg==0) ? (alpha + endv[j]) : -1e30f;
  float m2 = -1e30f;
  for (int k=0;k<25;k++) m2 = fmaxf(m2, __shfl(val, k, 64));
  float s2 = 0.f;
  for (int k=0;k<25;k++) s2 += __expf(__shfl(val, k, 64) - m2);
  float logZ = __logf(s2) + m2;
  const int* tg = tag + s*256;
  float gp = 0.f;
  for (int t=lane; t<256; t+=64){
    int a = tg[t];
    gp += emb[t*25 + a];
    if (t<255) gp += trans[a*25 + tg[t+1]];
  }
  #pragma unroll
  for (int off=32; off; off>>=1) gp += __shfl_xor(gp, off, 64);
  if (lane==0){
    float gold = gp + start[tg[0]] + endv[tg[255]];
    part[s] = logZ - gold;
  }
}

// ---------------- Kernel 7: final reduce
__global__ __launch_bounds__(64) void k_red(const float* __restrict__ part, float* __restrict__ out){
  float v = part[threadIdx.x];
  #pragma unroll
  for (int off=32; off; off>>=1) v += __shfl_xor(v, off, 64);
  if (threadIdx.x==0) out[0] = v;
}

extern "C" void kernel_launch(void* const* d_in, const int* in_sizes, int n_in,
                              void* d_out, int out_size, void* d_ws, size_t ws_size,
                              hipStream_t stream){
  const int* tok          = (const int*)d_in[0];
  const int* tagp         = (const int*)d_in[1];
  const int* char_tensor  = (const int*)d_in[3];
  const int* char_lengths = (const int*)d_in[4];
  const int* recover      = (const int*)d_in[5];
  const float* word_emb = (const float*)d_in[6];
  const float* char_emb = (const float*)d_in[7];
  const float* cWih_f=(const float*)d_in[8];  const float* cWhh_f=(const float*)d_in[9];  const float* cb_f=(const float*)d_in[10];
  const float* cWih_b=(const float*)d_in[11]; const float* cWhh_b=(const float*)d_in[12]; const float* cb_b=(const float*)d_in[13];
  const float* wWih_f=(const float*)d_in[14]; const float* wWhh_f=(const float*)d_in[15]; const float* wb_f=(const float*)d_in[16];
  const float* wWih_b=(const float*)d_in[17]; const float* wWhh_b=(const float*)d_in[18]; const float* wb_b=(const float*)d_in[19];
  const float* W_tag=(const float*)d_in[20];  const float* b_tag=(const float*)d_in[21];
  const float* trans=(const float*)d_in[22];  const float* startv=(const float*)d_in[23]; const float* endv=(const float*)d_in[24];

  float* ws  = (float*)d_ws;
  float* gxc = ws;                 // 25600
  float* cf  = ws + 25600;         // 16384*56 = 917504
  float* x   = ws + 943104;        // 2457600
  float* gx  = ws + 3400704;       // 13107200
  float* hseq= ws + 16507904;      // 3276800
  float* em  = ws + 943104;        // overlays x (dead after k_wih), 409600
  float* part= ws + 19784704;      // 64   (high water ~79.1 MB)
  float* out = (float*)d_out;

  k_gxc   <<<100, 256, 0, stream>>>(char_emb, cWih_f, cb_f, cWih_b, cb_b, gxc);
  k_char  <<<6554,512, 0, stream>>>(char_tensor, char_lengths, cWhh_f, cWhh_b, gxc, cf);
  k_buildx<<<9600,256, 0, stream>>>(tok, recover, word_emb, cf, x);
  k_wih   <<<2048,256, 0, stream>>>(x, wWih_f, wb_f, wWih_b, wb_b, gx);
  k_wlstm <<<128, 256, 0, stream>>>(gx, wWhh_f, wWhh_b, hseq);
  k_em    <<<2048,256, 0, stream>>>(hseq, W_tag, b_tag, em);
  k_crf   <<<64,  64,  0, stream>>>(em, tagp, trans, startv, endv, part);
  k_red   <<<1,   64,  0, stream>>>(part, out);
}